// Round 17
// baseline (480.654 us; speedup 1.0000x reference)
//
#include <hip/hip_runtime.h>
#include <cstddef>
#include <cstdint>

#define D_MODEL 256
#define LQ 19950
#define NBATCH 2
#define NT (NBATCH*LQ)

typedef short  bf16x8 __attribute__((ext_vector_type(8)));
typedef float  f32x4  __attribute__((ext_vector_type(4)));
typedef unsigned short u16x8 __attribute__((ext_vector_type(8)));
typedef unsigned short u16x4 __attribute__((ext_vector_type(4)));
typedef _Float16 h16x2 __attribute__((ext_vector_type(2)));

__device__ __forceinline__ unsigned short f2b(float f) {
  unsigned u = __float_as_uint(f);
  u += 0x7fff + ((u >> 16) & 1);          // RNE
  return (unsigned short)(u >> 16);
}
__device__ __forceinline__ float b2f(unsigned short s) {
  return __uint_as_float(((unsigned)s) << 16);
}
__device__ __forceinline__ bf16x8 pack8(float4 a, float4 b) {
  bf16x8 r;
  r[0]=(short)f2b(a.x); r[1]=(short)f2b(a.y); r[2]=(short)f2b(a.z); r[3]=(short)f2b(a.w);
  r[4]=(short)f2b(b.x); r[5]=(short)f2b(b.y); r[6]=(short)f2b(b.z); r[7]=(short)f2b(b.w);
  return r;
}

// ---- global->LDS 16B staging (wave-uniform LDS base + lane*16) ----
#if __has_builtin(__builtin_amdgcn_global_load_lds)
#define HAVE_GLL 1
__device__ __forceinline__ void gload16(const void* g, void* lds_base_uniform) {
  __builtin_amdgcn_global_load_lds(
      (const __attribute__((address_space(1))) void*)g,
      (__attribute__((address_space(3))) void*)lds_base_uniform, 16, 0, 0);
}
#else
#define HAVE_GLL 0
#endif

// ================= 64x64 bf16-MFMA GEMM (l2 proj only, K-split) =====
template<bool ABF, int BMODE, bool CBF, bool RELU, bool ROWBIAS>
__global__ __launch_bounds__(256) void mgemm(
    const void* __restrict__ Av, const void* __restrict__ Bv,
    const float* __restrict__ bias, void* __restrict__ Cv,
    int M, int N, int K, int lda, int ldb, long sB, long sC, int zShift)
{
  __shared__ unsigned short As[64][72];
  __shared__ unsigned short Bs[64][72];
  const int tid = threadIdx.x;
  const int n0 = blockIdx.x * 64, m0 = blockIdx.y * 64;
  const int zb = blockIdx.z;
  const int n_b = zb >> zShift;
  const int kBase = (zb & ((1 << zShift) - 1)) * K;
  const int lane = tid & 63;
  const int wave = tid >> 6;
  const int l15 = lane & 15, q = lane >> 4;
  const int m_off = (wave >> 1) * 32, n_off = (wave & 1) * 32;
  f32x4 acc[2][2] = {};

  for (int k0 = kBase; k0 < kBase + K; k0 += 64) {
    {
      int row = tid >> 2, kc = (tid & 3) * 8;
      int gm = m0 + row;
      bf16x8 v0 = (bf16x8)0, v1 = (bf16x8)0;
      if (gm < M) {
        if constexpr (ABF) {
          const unsigned short* A = (const unsigned short*)Av;
          v0 = *(const bf16x8*)&A[(size_t)gm*lda + k0 + kc];
          v1 = *(const bf16x8*)&A[(size_t)gm*lda + k0 + kc + 32];
        } else {
          const float* A = (const float*)Av;
          const float* p = &A[(size_t)gm*lda + k0 + kc];
          v0 = pack8(*(const float4*)p,      *(const float4*)(p+4));
          v1 = pack8(*(const float4*)(p+32), *(const float4*)(p+36));
        }
      }
      *(bf16x8*)&As[row][kc]    = v0;
      *(bf16x8*)&As[row][kc+32] = v1;
    }
    if constexpr (BMODE == 1) {
      const float* Bp = (const float*)Bv + (size_t)n_b * sB;
      int kr = tid >> 3, nc = (tid & 7) * 8;
      #pragma unroll
      for (int half = 0; half < 2; ++half) {
        int kk = kr + half*32;
        const float* p = &Bp[(size_t)(k0+kk)*ldb + n0 + nc];
        float v[8];
        if (n0 + nc + 7 < N) {
          float2 a0 = *(const float2*)p,     a1 = *(const float2*)(p+2);
          float2 a2 = *(const float2*)(p+4), a3 = *(const float2*)(p+6);
          v[0]=a0.x; v[1]=a0.y; v[2]=a1.x; v[3]=a1.y;
          v[4]=a2.x; v[5]=a2.y; v[6]=a3.x; v[7]=a3.y;
        } else {
          #pragma unroll
          for (int i=0;i<8;++i) v[i] = (n0+nc+i < N) ? p[i] : 0.f;
        }
        #pragma unroll
        for (int i=0;i<8;++i) Bs[nc+i][kk] = f2b(v[i]);
      }
    }
    __syncthreads();
    #pragma unroll
    for (int s = 0; s < 2; ++s) {
      bf16x8 a0 = *(const bf16x8*)&As[m_off      + l15][s*32 + q*8];
      bf16x8 a1 = *(const bf16x8*)&As[m_off + 16 + l15][s*32 + q*8];
      bf16x8 b0 = *(const bf16x8*)&Bs[n_off      + l15][s*32 + q*8];
      bf16x8 b1 = *(const bf16x8*)&Bs[n_off + 16 + l15][s*32 + q*8];
      acc[0][0] = __builtin_amdgcn_mfma_f32_16x16x32_bf16(a0, b0, acc[0][0], 0,0,0);
      acc[0][1] = __builtin_amdgcn_mfma_f32_16x16x32_bf16(a0, b1, acc[0][1], 0,0,0);
      acc[1][0] = __builtin_amdgcn_mfma_f32_16x16x32_bf16(a1, b0, acc[1][0], 0,0,0);
      acc[1][1] = __builtin_amdgcn_mfma_f32_16x16x32_bf16(a1, b1, acc[1][1], 0,0,0);
    }
    __syncthreads();
  }
  float* Cf = (float*)Cv + (size_t)zb * sC;
  unsigned short* Cb = (unsigned short*)Cv + (size_t)zb * sC;
  #pragma unroll
  for (int r = 0; r < 2; ++r) {
    #pragma unroll
    for (int c = 0; c < 2; ++c) {
      #pragma unroll
      for (int v = 0; v < 4; ++v) {
        int gm = m0 + m_off + r*16 + q*4 + v;
        int gn = n0 + n_off + c*16 + l15;
        if (gm < M && gn < N) {
          float o = acc[r][c][v];
          if (bias) o += ROWBIAS ? bias[gm] : bias[gn];
          if (RELU) o = fmaxf(o, 0.f);
          if constexpr (CBF) Cb[(size_t)gm*N + gn] = f2b(o);
          else               Cf[(size_t)gm*N + gn] = o;
        }
      }
    }
  }
}

// ---------- split-K reduce (l2) -> s2[o][n*HW+hw] layout ----------
__global__ __launch_bounds__(256) void proj_reduce2(
    const float* __restrict__ part, const float* __restrict__ bias,
    float* __restrict__ out, int HW, int S)
{
  int half = HW >> 1;
  int per_n = D_MODEL * half;
  int total = NBATCH * per_n;
  const float2* p2 = (const float2*)part;
  float2* o2 = (float2*)out;
  for (int i = blockIdx.x*256 + threadIdx.x; i < total; i += gridDim.x*256) {
    int n = i / per_n;
    int r = i - n*per_n;
    int o = r / half;
    int hw2 = r - o*half;
    float ax = 0.f, ay = 0.f;
    for (int s = 0; s < S; ++s) {
      float2 v = p2[((size_t)(n*S+s)*D_MODEL + o)*half + hw2];
      ax += v.x; ay += v.y;
    }
    float b = bias[o];
    o2[(size_t)o*HW + (size_t)n*half + hw2] = make_float2(ax+b, ay+b);
  }
}

// ======= 128x128 bf16xbf16 GEMM: single-buffer 32 KB LDS =======
template<bool CBF, bool RELU, bool RB>
__global__ __launch_bounds__(512) void gemm_bb(
    const unsigned short* __restrict__ A, const unsigned short* __restrict__ B,
    const float* __restrict__ bias, void* __restrict__ Cv,
    int M, int N, int K, int lda, int ldb)
{
  __shared__ unsigned short SA[8192];
  __shared__ unsigned short SB[8192];
  const int tid = threadIdx.x;
  const int lane = tid & 63, wave = tid >> 6;
  const int nwg = gridDim.x * gridDim.y;
  const int flat = blockIdx.y * gridDim.x + blockIdx.x;
  const int qn = nwg >> 3, rr = nwg & 7;
  const int xcd = flat & 7, lid = flat >> 3;
  const int swz = (xcd < rr ? xcd*(qn+1) : rr*(qn+1) + (xcd-rr)*qn) + lid;
  const int n0 = (swz % gridDim.x) * 128;
  const int m0 = (swz / gridDim.x) * 128;

  const int l15 = lane & 15, q = lane >> 4;
  const int m_off = (wave >> 2) * 64, n_off = (wave & 3) * 32;
  const int sr = lane >> 3;
  const int ssl = (lane & 7) ^ sr;
  const int rs = l15 & 7;
  f32x4 acc[4][2] = {};

  for (int k0 = 0; k0 < K; k0 += 64) {
    #pragma unroll
    for (int c = 0; c < 2; ++c) {
      int ch = wave*2 + c;
      const unsigned short* ga = A + (size_t)(m0 + ch*8 + sr)*lda + k0 + ssl*8;
      const unsigned short* gb = B + (size_t)(n0 + ch*8 + sr)*ldb + k0 + ssl*8;
#if HAVE_GLL
      gload16(ga, &SA[ch*512]);
      gload16(gb, &SB[ch*512]);
#else
      *(bf16x8*)&SA[ch*512 + lane*8] = *(const bf16x8*)ga;
      *(bf16x8*)&SB[ch*512 + lane*8] = *(const bf16x8*)gb;
#endif
    }
    __syncthreads();
    #pragma unroll
    for (int s = 0; s < 2; ++s) {
      int ps = ((s*4 + q) ^ rs) * 8;
      bf16x8 af[4], bfr[2];
      #pragma unroll
      for (int i = 0; i < 4; ++i)
        af[i] = *(const bf16x8*)&SA[(m_off + i*16 + l15)*64 + ps];
      #pragma unroll
      for (int j = 0; j < 2; ++j)
        bfr[j] = *(const bf16x8*)&SB[(n_off + j*16 + l15)*64 + ps];
      #pragma unroll
      for (int i = 0; i < 4; ++i)
        #pragma unroll
        for (int j = 0; j < 2; ++j)
          acc[i][j] = __builtin_amdgcn_mfma_f32_16x16x32_bf16(af[i], bfr[j], acc[i][j], 0,0,0);
    }
    __syncthreads();
  }

  float* Cf = (float*)Cv;
  unsigned short* Cb = (unsigned short*)Cv;
  #pragma unroll
  for (int i = 0; i < 4; ++i) {
    #pragma unroll
    for (int j = 0; j < 2; ++j) {
      #pragma unroll
      for (int v = 0; v < 4; ++v) {
        int gm = m0 + m_off + i*16 + q*4 + v;
        int gn = n0 + n_off + j*16 + l15;
        if (gm < M && gn < N) {
          float o = acc[i][j][v];
          if (bias) o += RB ? bias[gm] : bias[gn];
          if (RELU) o = fmaxf(o, 0.f);
          if constexpr (CBF) Cb[(size_t)gm*N + gn] = f2b(o);
          else               Cf[(size_t)gm*N + gn] = o;
        }
      }
    }
  }
}

// ======= 128x256 wide-N GEMM: single-buffer 48 KB LDS, wave tile 64x64 =======
// For FFN1 / fc / proj l0,l1 (N large). Same swizzles as gemm_bb.
// B overreads up to 255 rows past N (must stay in buffer region); C guarded.
template<bool CBF, bool RELU, bool RB>
__global__ __launch_bounds__(512) void gemm_wide(
    const unsigned short* __restrict__ A, const unsigned short* __restrict__ B,
    const float* __restrict__ bias, void* __restrict__ Cv,
    int M, int N, int K, int lda, int ldb)
{
  __shared__ unsigned short SA[8192];    // 128 x 64
  __shared__ unsigned short SB[16384];   // 256 x 64
  const int tid = threadIdx.x;
  const int lane = tid & 63, wave = tid >> 6;
  const int nwg = gridDim.x * gridDim.y;
  const int flat = blockIdx.y * gridDim.x + blockIdx.x;
  const int qn = nwg >> 3, rr = nwg & 7;
  const int xcd = flat & 7, lid = flat >> 3;
  const int swz = (xcd < rr ? xcd*(qn+1) : rr*(qn+1) + (xcd-rr)*qn) + lid;
  const int n0 = (swz % gridDim.x) * 256;
  const int m0 = (swz / gridDim.x) * 128;

  const int l15 = lane & 15, q = lane >> 4;
  const int m_off = (wave >> 2) * 64, n_off = (wave & 3) * 64;
  const int sr = lane >> 3;
  const int ssl = (lane & 7) ^ sr;
  const int rs = l15 & 7;
  f32x4 acc[4][4] = {};

  for (int k0 = 0; k0 < K; k0 += 64) {
    #pragma unroll
    for (int c = 0; c < 2; ++c) {
      int ch = wave*2 + c;                         // A chunks 0..15
      const unsigned short* ga = A + (size_t)(m0 + ch*8 + sr)*lda + k0 + ssl*8;
#if HAVE_GLL
      gload16(ga, &SA[ch*512]);
#else
      *(bf16x8*)&SA[ch*512 + lane*8] = *(const bf16x8*)ga;
#endif
    }
    #pragma unroll
    for (int c = 0; c < 4; ++c) {
      int ch = wave*4 + c;                         // B chunks 0..31
      const unsigned short* gb = B + (size_t)(n0 + ch*8 + sr)*ldb + k0 + ssl*8;
#if HAVE_GLL
      gload16(gb, &SB[ch*512]);
#else
      *(bf16x8*)&SB[ch*512 + lane*8] = *(const bf16x8*)gb;
#endif
    }
    __syncthreads();
    #pragma unroll
    for (int s = 0; s < 2; ++s) {
      int ps = ((s*4 + q) ^ rs) * 8;
      bf16x8 af[4], bfr[4];
      #pragma unroll
      for (int i = 0; i < 4; ++i)
        af[i] = *(const bf16x8*)&SA[(m_off + i*16 + l15)*64 + ps];
      #pragma unroll
      for (int j = 0; j < 4; ++j)
        bfr[j] = *(const bf16x8*)&SB[(n_off + j*16 + l15)*64 + ps];
      #pragma unroll
      for (int i = 0; i < 4; ++i)
        #pragma unroll
        for (int j = 0; j < 4; ++j)
          acc[i][j] = __builtin_amdgcn_mfma_f32_16x16x32_bf16(af[i], bfr[j], acc[i][j], 0,0,0);
    }
    __syncthreads();
  }

  float* Cf = (float*)Cv;
  unsigned short* Cb = (unsigned short*)Cv;
  #pragma unroll
  for (int i = 0; i < 4; ++i) {
    #pragma unroll
    for (int j = 0; j < 4; ++j) {
      #pragma unroll
      for (int v = 0; v < 4; ++v) {
        int gm = m0 + m_off + i*16 + q*4 + v;
        int gn = n0 + n_off + j*16 + l15;
        if (gm < M && gn < N) {
          float o = acc[i][j][v];
          if (bias) o += RB ? bias[gm] : bias[gn];
          if (RELU) o = fmaxf(o, 0.f);
          if constexpr (CBF) Cb[(size_t)gm*N + gn] = f2b(o);
          else               Cf[(size_t)gm*N + gn] = o;
        }
      }
    }
  }
}

// ======= merged value + off/attn GEMM (single-buffer, K=256) =======
__global__ __launch_bounds__(512) void gemm_vo(
    const unsigned short* __restrict__ Asrc, const unsigned short* __restrict__ Aq,
    const unsigned short* __restrict__ Bv,   const unsigned short* __restrict__ Bo,
    const float* __restrict__ bias_v, const float* __restrict__ bias_o,
    unsigned short* __restrict__ Cv, unsigned short* __restrict__ Co, int M)
{
  __shared__ unsigned short SA[8192];
  __shared__ unsigned short SB[8192];
  const int tid = threadIdx.x;
  const int lane = tid & 63, wave = tid >> 6;
  const int nwg = gridDim.x * gridDim.y;
  const int flat = blockIdx.y * gridDim.x + blockIdx.x;
  const int qn = nwg >> 3, rr = nwg & 7;
  const int xcd = flat & 7, lid = flat >> 3;
  const int swz = (xcd < rr ? xcd*(qn+1) : rr*(qn+1) + (xcd-rr)*qn) + lid;
  const int colid = swz % gridDim.x;
  const int m0 = (swz / gridDim.x) * 128;

  const unsigned short* A; const unsigned short* B;
  const float* bias; unsigned short* C; int N, n0; bool isv;
  if (colid < 2) { A = Asrc; B = Bv; bias = bias_v; C = Cv; N = 256; n0 = colid*128; isv = true; }
  else           { A = Aq;   B = Bo; bias = bias_o; C = Co; N = 288; n0 = (colid-2)*128; isv = false; }

  const int l15 = lane & 15, q = lane >> 4;
  const int m_off = (wave >> 2) * 64, n_off = (wave & 3) * 32;
  const int sr = lane >> 3;
  const int ssl = (lane & 7) ^ sr;
  const int rs = l15 & 7;
  f32x4 acc[4][2] = {};

  for (int k0 = 0; k0 < 256; k0 += 64) {
    #pragma unroll
    for (int c = 0; c < 2; ++c) {
      int ch = wave*2 + c;
      const unsigned short* ga = A + (size_t)(m0 + ch*8 + sr)*256 + k0 + ssl*8;
      const unsigned short* gb = B + (size_t)(n0 + ch*8 + sr)*256 + k0 + ssl*8;
#if HAVE_GLL
      gload16(ga, &SA[ch*512]);
      gload16(gb, &SB[ch*512]);
#else
      *(bf16x8*)&SA[ch*512 + lane*8] = *(const bf16x8*)ga;
      *(bf16x8*)&SB[ch*512 + lane*8] = *(const bf16x8*)gb;
#endif
    }
    __syncthreads();
    #pragma unroll
    for (int s = 0; s < 2; ++s) {
      int ps = ((s*4 + q) ^ rs) * 8;
      bf16x8 af[4], bfr[2];
      #pragma unroll
      for (int i = 0; i < 4; ++i)
        af[i] = *(const bf16x8*)&SA[(m_off + i*16 + l15)*64 + ps];
      #pragma unroll
      for (int j = 0; j < 2; ++j)
        bfr[j] = *(const bf16x8*)&SB[(n_off + j*16 + l15)*64 + ps];
      #pragma unroll
      for (int i = 0; i < 4; ++i)
        #pragma unroll
        for (int j = 0; j < 2; ++j)
          acc[i][j] = __builtin_amdgcn_mfma_f32_16x16x32_bf16(af[i], bfr[j], acc[i][j], 0,0,0);
    }
    __syncthreads();
  }

  #pragma unroll
  for (int i = 0; i < 4; ++i) {
    #pragma unroll
    for (int j = 0; j < 2; ++j) {
      #pragma unroll
      for (int v = 0; v < 4; ++v) {
        int gm = m0 + m_off + i*16 + q*4 + v;
        int gn = n0 + n_off + j*16 + l15;
        if (gm < M && gn < N) {
          float o = acc[i][j][v] + bias[gn];
          unsigned short bits;
          if (isv) { _Float16 hh = (_Float16)o; bits = *(unsigned short*)&hh; }
          else     { bits = f2b(o); }
          C[(size_t)gm*N + gn] = bits;
        }
      }
    }
  }
}

// ---------- feat [C,HW] fp32 -> featT [n*HW+hw][C] bf16 ----------
__global__ __launch_bounds__(256) void tconv(
    const float* __restrict__ feat, unsigned short* __restrict__ featT,
    int C, int HW)
{
  __shared__ float T[32][33];
  int hw0 = blockIdx.x*32, c0 = blockIdx.y*32, n = blockIdx.z;
  const float* base = feat + (size_t)n*C*HW;
  int tx = threadIdx.x & 31, ty = threadIdx.x >> 5;
  #pragma unroll
  for (int it=0; it<4; ++it) {
    int c = c0 + ty + it*8;
    int hw = hw0 + tx;
    T[ty+it*8][tx] = (hw < HW) ? base[(size_t)c*HW + hw] : 0.f;
  }
  __syncthreads();
  #pragma unroll
  for (int it=0; it<4; ++it) {
    int tl = ty + it*8;
    int tok = hw0 + tl;
    if (tok < HW) {
      featT[((size_t)n*HW + tok)*C + c0 + tx] = f2b(T[tx][tl]);
    }
  }
}

// ---------- one-time weight fp32->bf16 conversion (9 segments) ----------
struct W9 { const float* src[9]; unsigned short* dst[9]; int nv[9]; };
__global__ __launch_bounds__(256) void wconv(W9 w)
{
  int s = blockIdx.y;
  const float4* src = (const float4*)w.src[s];
  unsigned short* dst = w.dst[s];
  int n = w.nv[s];
  for (int i = blockIdx.x*256 + threadIdx.x; i < n; i += gridDim.x*256) {
    float4 v = src[i];
    u16x4 o = { f2b(v.x), f2b(v.y), f2b(v.z), f2b(v.w) };
    *(u16x4*)(dst + (size_t)i*4) = o;
  }
}

// ---------- concat off/attn biases ----------
__global__ __launch_bounds__(288) void biascat(
    const float* __restrict__ b_off, const float* __restrict__ b_attn,
    float* __restrict__ out)
{
  int i = threadIdx.x;
  out[i] = (i < 192) ? b_off[i] : b_attn[i - 192];
}

// ---------- GN stage 1 over s2[o][n*HW+hw] layout ----------
__global__ __launch_bounds__(256) void gn_partial2(
    const float* __restrict__ s2, float* __restrict__ partials, int HW)
{
  int g = blockIdx.x, n = blockIdx.y, c = blockIdx.z;
  int NHW = HW*2;
  int nvec2 = HW >> 1;
  int total = nvec2*8;
  float sum = 0.f, sq = 0.f;
  for (int j = c*256 + threadIdx.x; j < total; j += 2048) {
    int r = j / nvec2;
    int v = j - r*nvec2;
    const float2 x = *(const float2*)(s2 + (size_t)(g*8+r)*NHW + (size_t)n*HW + v*2);
    sum += x.x + x.y;
    sq  += x.x*x.x + x.y*x.y;
  }
  #pragma unroll
  for (int m=32;m;m>>=1){ sum += __shfl_xor(sum,m,64); sq += __shfl_xor(sq,m,64); }
  __shared__ float s1[4], s2s[4];
  int w = threadIdx.x >> 6;
  if ((threadIdx.x & 63) == 0) { s1[w]=sum; s2s[w]=sq; }
  __syncthreads();
  if (threadIdx.x == 0) {
    partials[(((size_t)n*32+g)*8 + c)*2]     = s1[0]+s1[1]+s1[2]+s1[3];
    partials[(((size_t)n*32+g)*8 + c)*2 + 1] = s2s[0]+s2s[1]+s2s[2]+s2s[3];
  }
}

// ---------- GN apply + transpose + FUSED q/src_bf emission ----------
// s2[o][n*HW+hw] -> src fp32 token-major, src_bf bf16, q bf16 (src+pos+lvl_emb)
__global__ __launch_bounds__(256) void gn_apply2(
    const float* __restrict__ s2, const float* __restrict__ partials,
    const float* __restrict__ gw, const float* __restrict__ gb,
    const float* __restrict__ le,             // level_embed + lvl*256
    float* __restrict__ src, unsigned short* __restrict__ srcbf,
    unsigned short* __restrict__ qb,
    int HW, int loff, int W, float invW, float invH2pi, float invW2pi)
{
  __shared__ float T[32][33];
  __shared__ float smu[4], srs[4];
  int tx = threadIdx.x & 31, ty = threadIdx.x >> 5;
  int hw0 = blockIdx.x*32, o0 = blockIdx.y*32, n = blockIdx.z;
  int NHW = HW*2;
  if (threadIdx.x < 4) {
    int g = (o0 >> 3) + threadIdx.x;
    float S = 0.f, Q = 0.f;
    #pragma unroll
    for (int c = 0; c < 8; ++c) {
      S += partials[(((size_t)n*32+g)*8 + c)*2];
      Q += partials[(((size_t)n*32+g)*8 + c)*2 + 1];
    }
    float inv = 1.f/(float)(8*HW);
    float mu = S*inv;
    float var = Q*inv - mu*mu;
    smu[threadIdx.x] = mu;
    srs[threadIdx.x] = rsqrtf(var + 1e-5f);
  }
  __syncthreads();
  #pragma unroll
  for (int it=0; it<4; ++it) {
    int ol = ty + it*8;
    int o = o0 + ol;
    int hw = hw0 + tx;
    float v = 0.f;
    if (hw < HW) {
      v = (s2[(size_t)o*NHW + (size_t)n*HW + hw] - smu[ol>>3])*srs[ol>>3]*gw[o] + gb[o];
    }
    T[ol][tx] = v;
  }
  __syncthreads();
  // pos-encoding per-thread constants (d = o0+tx fixed)
  int d = o0 + tx;
  int m = (d & 127) >> 1;
  float invt = __expf((float)m * -0.14391156516f);   // 10000^(-m/64)
  float lev  = le[d];
  #pragma unroll
  for (int it=0; it<4; ++it) {
    int tl = ty + it*8;
    int tok = hw0 + tl;
    if (tok < HW) {
      size_t idx = ((size_t)n*LQ + loff + tok)*D_MODEL + d;
      float v = T[tx][tl];
      src[idx] = v;
      srcbf[idx] = f2b(v);
      int i = __float2int_rd(((float)tok + 0.5f) * invW);
      int j = tok - i*W;
      float ang = ((d < 128) ? (float)(i+1)*invH2pi : (float)(j+1)*invW2pi) * invt;
      float pe = (d & 1) ? __cosf(ang) : __sinf(ang);
      qb[idx] = f2b(v + pe + lev);
    }
  }
}

// ---------- deformable sampling v3: fp16 value + packed v_pk_fma_f16 ----------
__global__ __launch_bounds__(256) void deform_sample(
    const unsigned short* __restrict__ value, const unsigned short* __restrict__ offaw,
    unsigned short* __restrict__ accb)
{
  int idx = blockIdx.x*256 + threadIdx.x;
  if (idx >= NT*8*4) return;
  int quarter = idx & 3;
  int h = (idx >> 2) & 7;
  int row = idx >> 5;
  int n = (row >= LQ) ? 1 : 0;
  int tok = row - n*LQ;

  float bxs0, bxs1, bxs2, bys0, bys1, bys2;
  if (tok < 15200) {
    int ti = tok/152, tj = tok - ti*152;
    float bx = tj + 0.5f, by = ti + 0.5f;
    bxs0 = bx - 0.5f;         bys0 = by - 0.5f;
    bxs1 = bx*0.5f - 0.5f;    bys1 = by*0.5f - 0.5f;
    bxs2 = bx*0.25f - 0.5f;   bys2 = by*0.25f - 0.5f;
  } else if (tok < 19000) {
    int hw = tok - 15200; int ti = hw/76, tj = hw - ti*76;
    float bx = tj + 0.5f, by = ti + 0.5f;
    bxs0 = bx*2.f - 0.5f;     bys0 = by*2.f - 0.5f;
    bxs1 = bx - 0.5f;         bys1 = by - 0.5f;
    bxs2 = bx*0.5f - 0.5f;    bys2 = by*0.5f - 0.5f;
  } else {
    int hw = tok - 19000; int ti = hw/38, tj = hw - ti*38;
    float bx = tj + 0.5f, by = ti + 0.5f;
    bxs0 = bx*4.f - 0.5f;     bys0 = by*4.f - 0.5f;
    bxs1 = bx*2.f - 0.5f;     bys1 = by*2.f - 0.5f;
    bxs2 = bx - 0.5f;         bys2 = by - 0.5f;
  }
  const float bxs[3] = {bxs0, bxs1, bxs2};
  const float bys[3] = {bys0, bys1, bys2};

  const unsigned short* offr = offaw + (size_t)row*288 + h*24;
  const unsigned short* awr  = offaw + (size_t)row*288 + 192 + h*12;
  float off[24];
  {
    u16x8 o0 = *(const u16x8*)offr;
    u16x8 o1 = *(const u16x8*)(offr+8);
    u16x8 o2 = *(const u16x8*)(offr+16);
    #pragma unroll
    for (int c=0;c<8;++c){ off[c]=b2f(o0[c]); off[8+c]=b2f(o1[c]); off[16+c]=b2f(o2[c]); }
  }
  float lg[12];
  {
    u16x4 a0 = *(const u16x4*)awr;
    u16x4 a1 = *(const u16x4*)(awr+4);
    u16x4 a2 = *(const u16x4*)(awr+8);
    #pragma unroll
    for (int c=0;c<4;++c){ lg[c]=b2f(a0[c]); lg[4+c]=b2f(a1[c]); lg[8+c]=b2f(a2[c]); }
  }
  float mx = -1e30f;
  #pragma unroll
  for (int i=0;i<12;++i) mx = fmaxf(mx, lg[i]);
  float ssum = 0.f;
  #pragma unroll
  for (int i=0;i<12;++i){ lg[i] = __expf(lg[i]-mx); ssum += lg[i]; }
  float sinv = 1.f/ssum;

  h16x2 acc2[4] = {};
  const int HH[3]={100,50,25}, WW[3]={152,76,38}, OO[3]={0,15200,19000};
  int chbase = h*32 + quarter*8;
  const _Float16* vhalf = (const _Float16*)value;
  #pragma unroll
  for (int lvl=0; lvl<3; ++lvl) {
    const int H=HH[lvl], W=WW[lvl], lo=OO[lvl];
    const _Float16* vbase = vhalf + ((size_t)(n*LQ + lo)*D_MODEL) + chbase;
    #pragma unroll
    for (int p=0; p<4; ++p) {
      float ox = off[lvl*8 + p*2];
      float oy = off[lvl*8 + p*2 + 1];
      float a  = lg[lvl*4 + p] * sinv;
      float x = bxs[lvl] + ox;
      float y = bys[lvl] + oy;
      float x0f = floorf(x), y0f = floorf(y);
      float wx = x - x0f, wy = y - y0f;
      int x0 = (int)x0f, y0 = (int)y0f;
      float w00 = (1.f-wx)*(1.f-wy)*a, w10 = wx*(1.f-wy)*a;
      float w01 = (1.f-wx)*wy*a,       w11 = wx*wy*a;
      if ((unsigned)x0 < (unsigned)(W-1) && (unsigned)y0 < (unsigned)(H-1)) {
        const h16x2* p00 = (const h16x2*)(vbase + (size_t)(y0*W + x0)*D_MODEL);
        const h16x2* p10 = (const h16x2*)(vbase + (size_t)(y0*W + x0 + 1)*D_MODEL);
        const h16x2* p01 = (const h16x2*)(vbase + (size_t)((y0+1)*W + x0)*D_MODEL);
        const h16x2* p11 = (const h16x2*)(vbase + (size_t)((y0+1)*W + x0 + 1)*D_MODEL);
        _Float16 h00 = (_Float16)w00, h10 = (_Float16)w10;
        _Float16 h01 = (_Float16)w01, h11 = (_Float16)w11;
        h16x2 wp00 = {h00,h00}, wp10 = {h10,h10}, wp01 = {h01,h01}, wp11 = {h11,h11};
        #pragma unroll
        for (int k=0;k<4;++k) {
          acc2[k] += wp00*p00[k];
          acc2[k] += wp10*p10[k];
          acc2[k] += wp01*p01[k];
          acc2[k] += wp11*p11[k];
        }
      } else {
        float tw[4] = { w00, w10, w01, w11 };
        #pragma unroll
        for (int t=0; t<4; ++t) {
          int xi = x0 + (t & 1), yi = y0 + (t >> 1);
          if (xi >= 0 && xi < W && yi >= 0 && yi < H) {
            _Float16 wh = (_Float16)tw[t];
            h16x2 wp = {wh, wh};
            const h16x2* vr = (const h16x2*)(vbase + (size_t)(yi*W + xi)*D_MODEL);
            #pragma unroll
            for (int k=0;k<4;++k) acc2[k] += wp*vr[k];
          }
        }
      }
    }
  }
  unsigned short* o = accb + (size_t)row*D_MODEL + chbase;
  u16x8 ov;
  #pragma unroll
  for (int k=0;k<4;++k) {
    ov[k*2]   = f2b((float)acc2[k][0]);
    ov[k*2+1] = f2b((float)acc2[k][1]);
  }
  *(u16x8*)o = ov;
}

// ---------- out = LN(A+B)*g+b (+ optional bf16 mirror) ----------
template<bool EMITBF>
__global__ __launch_bounds__(256) void ln_add(
    const float* __restrict__ A, const float* __restrict__ B,
    const float* __restrict__ g, const float* __restrict__ b,
    float* __restrict__ out, unsigned short* __restrict__ outbf, int rows)
{
  int wid = (blockIdx.x * 256 + threadIdx.x) >> 6;
  int lane = threadIdx.x & 63;
  if (wid >= rows) return;
  size_t base = (size_t)wid * D_MODEL;
  float4 va = *(const float4*)&A[base + lane*4];
  float4 vb = *(const float4*)&B[base + lane*4];
  float v[4] = {va.x+vb.x, va.y+vb.y, va.z+vb.z, va.w+vb.w};
  float s = v[0]+v[1]+v[2]+v[3];
  #pragma unroll
  for (int m=32; m; m>>=1) s += __shfl_xor(s, m, 64);
  float mu = s * (1.f/256.f);
  float qq = 0.f;
  #pragma unroll
  for (int i=0;i<4;++i){ float d=v[i]-mu; qq += d*d; }
  #pragma unroll
  for (int m=32; m; m>>=1) qq += __shfl_xor(qq, m, 64);
  float rstd = rsqrtf(qq*(1.f/256.f) + 1e-5f);
  float o[4];
  #pragma unroll
  for (int i=0;i<4;++i){
    int d = lane*4+i;
    o[i] = (v[i]-mu)*rstd*g[d] + b[d];
  }
  *(float4*)&out[base + lane*4] = make_float4(o[0],o[1],o[2],o[3]);
  if constexpr (EMITBF) {
    u16x4 ob = { f2b(o[0]), f2b(o[1]), f2b(o[2]), f2b(o[3]) };
    *(u16x4*)&outbf[base + lane*4] = ob;
  }
}

// ---------- point head bilinear (bf16 out) ----------
__global__ __launch_bounds__(256) void point_sample(
    const float* __restrict__ x2, const float* __restrict__ pc,
    unsigned short* __restrict__ pf)
{
  int pidx = blockIdx.x;
  int n = pidx / 1000;
  float px = pc[(size_t)pidx*2], py = pc[(size_t)pidx*2+1];
  float x = ((2.f*px)*152.f - 1.f)*0.5f;
  float y = ((2.f*py)*100.f - 1.f)*0.5f;
  float x0f=floorf(x), y0f=floorf(y);
  float wx=x-x0f, wy=y-y0f;
  int x0=(int)x0f, y0=(int)y0f;
  int d = threadIdx.x;
  float accv = 0.f;
  #pragma unroll
  for (int t=0;t<4;++t) {
    int xi = x0 + (t&1), yi = y0 + (t>>1);
    float w = ((t&1)?wx:(1.f-wx)) * ((t>>1)?wy:(1.f-wy));
    if (xi>=0 && xi<152 && yi>=0 && yi<100) {
      accv += w * x2[((size_t)(n*LQ + yi*152 + xi))*D_MODEL + d];
    }
  }
  pf[(size_t)pidx*D_MODEL + d] = f2b(accv);
}

__global__ void copy_gt(const int* __restrict__ gt, float* __restrict__ out, int nels)
{
  int i = blockIdx.x*256 + threadIdx.x;
  if (i < nels) out[i] = (float)gt[i];
}

extern "C" void kernel_launch(void* const* d_in, const int* in_sizes, int n_in,
                              void* d_out, int out_size, void* d_ws, size_t ws_size,
                              hipStream_t stream)
{
  const float* feat[3]  = {(const float*)d_in[0], (const float*)d_in[1], (const float*)d_in[2]};
  const float* pc       = (const float*)d_in[3];
  const int*   gt       = (const int*)d_in[4];
  const float* projw[3] = {(const float*)d_in[5],  (const float*)d_in[9],  (const float*)d_in[13]};
  const float* projb[3] = {(const float*)d_in[6],  (const float*)d_in[10], (const float*)d_in[14]};
  const float* gng[3]   = {(const float*)d_in[7],  (const float*)d_in[11], (const float*)d_in[15]};
  const float* gnb[3]   = {(const float*)d_in[8],  (const float*)d_in[12], (const float*)d_in[16]};
  const float* level_embed = (const float*)d_in[17];
  const float* w_off  = (const float*)d_in[18];
  const float* b_off  = (const float*)d_in[19];
  const float* w_attn = (const float*)d_in[20];
  const float* b_attn = (const float*)d_in[21];
  const float* w_val  = (const float*)d_in[22];
  const float* b_val  = (const float*)d_in[23];
  const float* w_out  = (const float*)d_in[24];
  const float* b_out  = (const float*)d_in[25];
  const float* ln1g   = (const float*)d_in[26];
  const float* ln1b   = (const float*)d_in[27];
  const float* ln2g   = (const float*)d_in[28];
  const float* ln2b   = (const float*)d_in[29];
  const float* wff1   = (const float*)d_in[30];
  const float* bff1   = (const float*)d_in[31];
  const float* wff2   = (const float*)d_in[32];
  const float* bff2   = (const float*)d_in[33];
  const float* fcw    = (const float*)d_in[34];
  const float* fcb    = (const float*)d_in[35];

  // ---- workspace layout ----
  float* ws    = (float*)d_ws;
  float* s_tmp = ws;                                             // 10,214,400 f
  unsigned short* q_b     = (unsigned short*)(s_tmp + 10214400); // 10,214,400 us
  unsigned short* value_b = q_b + 10214400;                      // 10,214,400 us
  float* srcb  = (float*)(value_b + 10214400);                   // 10,214,400 f
  float* xreg  = srcb + 10214400;                                // 10,214,400 f
  unsigned short* offaw   = (unsigned short*)(xreg + 10214400);  // 11,491,200 us
  unsigned short* wbf     = offaw + 11491200;                    //  4,333,568 us
  float* partials = (float*)(wbf + 4333568);                     // 1024 f
  float* boffaw   = partials + 1024;                             // 288 f

  unsigned short* wv_bf  = wbf;
  unsigned short* wof_bf = wbf + 65536;
  unsigned short* wat_bf = wbf + 114688;
  unsigned short* wou_bf = wbf + 139264;
  unsigned short* wf1_bf = wbf + 204800;
  unsigned short* wf2_bf = wbf + 466944;
  unsigned short* wfc_bf = wbf + 729088;
  unsigned short* wp0_bf = wbf + 3940352;   // 131,072 us (256x512)
  unsigned short* wp1_bf = wbf + 4071424;   // 262,144 us (256x1024)

  unsigned short* featT = q_b;                       // proj phase (gemm_wide writes q later)
  float* kpart = (float*)offaw;                      // l2 split-K partials (offaw idle in proj)
  unsigned short* src_bf = (unsigned short*)xreg;    // bf16 src mirror (written in gn_apply2)
  unsigned short* acc_b = q_b;                       // q dead after step 3
  unsigned short* xb_bf = offaw;                     // off/aw dead after step 4
  unsigned short* hbuf  = (unsigned short*)s_tmp;    // FULL h spans s_tmp+q_b+value_b
  unsigned short* pf    = value_b;                   // h dead after FFN2
  float* ybuf = srcb;                                // src dead after LN1
  float* x2   = s_tmp;                               // h dead after FFN2

  // 0) weight conversion + bias concat
  W9 w9;
  w9.src[0]=w_val;    w9.dst[0]=wv_bf;  w9.nv[0]=65536/4;
  w9.src[1]=w_off;    w9.dst[1]=wof_bf; w9.nv[1]=49152/4;
  w9.src[2]=w_attn;   w9.dst[2]=wat_bf; w9.nv[2]=24576/4;
  w9.src[3]=w_out;    w9.dst[3]=wou_bf; w9.nv[3]=65536/4;
  w9.src[4]=wff1;     w9.dst[4]=wf1_bf; w9.nv[4]=262144/4;
  w9.src[5]=wff2;     w9.dst[5]=wf2_bf; w9.nv[5]=262144/4;
  w9.src[6]=fcw;      w9.dst[6]=wfc_bf; w9.nv[6]=3211264/4;
  w9.src[7]=projw[0]; w9.dst[7]=wp0_bf; w9.nv[7]=131072/4;
  w9.src[8]=projw[1]; w9.dst[8]=wp1_bf; w9.nv[8]=262144/4;
  wconv<<<dim3(512, 9), 256, 0, stream>>>(w9);
  biascat<<<1, 288, 0, stream>>>(b_off, b_attn, boffaw);

  const float PI2 = 6.28318530717958647692f;
  // 1) proj levels (gn_apply2 fused with q/src_bf emission)
  {  // level 0: HW=15200, K=512, W=152, H=100
    tconv<<<dim3(475, 16, 2), 256, 0, stream>>>(feat[0], featT, 512, 15200);
    gemm_wide<false,false,true><<<dim3(119, 2), 512, 0, stream>>>(
        wp0_bf, featT, projb[0], s_tmp, 256, 30400, 512, 512, 512);
    gn_partial2<<<dim3(32, 2, 8), 256, 0, stream>>>(s_tmp, partials, 15200);
    gn_apply2<<<dim3(475, 8, 2), 256, 0, stream>>>(
        s_tmp, partials, gng[0], gnb[0], level_embed, srcb, src_bf, q_b,
        15200, 0, 152, 1.0f/152.f, PI2/(100.f+1e-6f), PI2/(152.f+1e-6f));
  }
  {  // level 1: HW=3800, K=1024, W=76, H=50
    tconv<<<dim3(119, 32, 2), 256, 0, stream>>>(feat[1], featT, 1024, 3800);
    gemm_wide<false,false,true><<<dim3(30, 2), 512, 0, stream>>>(
        wp1_bf, featT, projb[1], s_tmp, 256, 7600, 1024, 1024, 1024);
    gn_partial2<<<dim3(32, 2, 8), 256, 0, stream>>>(s_tmp, partials, 3800);
    gn_apply2<<<dim3(119, 8, 2), 256, 0, stream>>>(
        s_tmp, partials, gng[1], gnb[1], level_embed + 256, srcb, src_bf, q_b,
        3800, 15200, 76, 1.0f/76.f, PI2/(50.f+1e-6f), PI2/(76.f+1e-6f));
  }
  {  // level 2: HW=950, K=2048, split-K S=4, W=38, H=25
    mgemm<false,1,false,false,true><<<dim3(15, 4, 8), 256, 0, stream>>>(
        projw[2], feat[2], nullptr, kpart, D_MODEL, 950, 512, 2048, 950,
        (long)2048*950, (long)D_MODEL*950, 2);
    int total2 = NBATCH * D_MODEL * (950 >> 1);
    int gr = (total2 + 255) / 256; if (gr > 2048) gr = 2048;
    proj_reduce2<<<gr, 256, 0, stream>>>(kpart, projb[2], s_tmp, 950, 4);
    gn_partial2<<<dim3(32, 2, 8), 256, 0, stream>>>(s_tmp, partials, 950);
    gn_apply2<<<dim3(30, 8, 2), 256, 0, stream>>>(
        s_tmp, partials, gng[2], gnb[2], level_embed + 512, srcb, src_bf, q_b,
        950, 19000, 38, 1.0f/38.f, PI2/(25.f+1e-6f), PI2/(38.f+1e-6f));
  }

  // 3) value (fp16 C) + off/attn (bf16 C) in ONE dispatch
  int gm128 = (NT + 127) / 128;
  gemm_vo<<<dim3(5, gm128), 512, 0, stream>>>(
      src_bf, q_b, wv_bf, wof_bf, b_val, boffaw, value_b, offaw, NT);

  // 4) deformable sampling (fp16 packed fma) -> acc bf16 (q region)
  deform_sample<<<(NT*8*4 + 255)/256, 256, 0, stream>>>(value_b, offaw, acc_b);

  // 5) out-proj ; x = LN(src + attn) -> xreg + xb_bf
  gemm_bb<false,false,false><<<dim3(2, gm128), 512, 0, stream>>>(
      acc_b, wou_bf, b_out, s_tmp, NT, 256, 256, 256, 256);
  ln_add<true><<<(NT+3)/4, 256, 0, stream>>>(srcb, s_tmp, ln1g, ln1b, xreg, xb_bf, NT);

  // 6) FFN, un-chunked: h spans s_tmp+q_b+value_b; y -> srcb
  gemm_wide<true,true,false><<<dim3(4, gm128), 512, 0, stream>>>(
      xb_bf, wf1_bf, bff1, hbuf, NT, 1024, 256, 256, 256);
  gemm_bb<false,false,false><<<dim3(2, gm128), 512, 0, stream>>>(
      hbuf, wf2_bf, bff2, ybuf, NT, 256, 1024, 1024, 1024);

  // 7) x2 = LN(x + y) -> s_tmp
  ln_add<false><<<(NT+3)/4, 256, 0, stream>>>(xreg, ybuf, ln2g, ln2b, x2, nullptr, NT);

  // 8) point bilinear -> pf bf16, fc GEMM (wide-N) -> d_out, gt tail
  point_sample<<<2000, 256, 0, stream>>>(x2, pc, pf);
  gemm_wide<false,true,false><<<dim3(49, (2000+127)/128), 512, 0, stream>>>(
      pf, wfc_bf, fcb, (float*)d_out, 2000, 12544, 256, 256, 256);
  copy_gt<<<8, 256, 0, stream>>>(gt, (float*)d_out + (size_t)2000*12544, 2000);
}

// Round 18
// 453.579 us; speedup vs baseline: 1.0597x; 1.0597x over previous
//
#include <hip/hip_runtime.h>
#include <cstddef>
#include <cstdint>

#define D_MODEL 256
#define LQ 19950
#define NBATCH 2
#define NT (NBATCH*LQ)

typedef short  bf16x8 __attribute__((ext_vector_type(8)));
typedef float  f32x4  __attribute__((ext_vector_type(4)));
typedef unsigned short u16x8 __attribute__((ext_vector_type(8)));
typedef unsigned short u16x4 __attribute__((ext_vector_type(4)));
typedef _Float16 h16x2 __attribute__((ext_vector_type(2)));

__device__ __forceinline__ unsigned short f2b(float f) {
  unsigned u = __float_as_uint(f);
  u += 0x7fff + ((u >> 16) & 1);          // RNE
  return (unsigned short)(u >> 16);
}
__device__ __forceinline__ float b2f(unsigned short s) {
  return __uint_as_float(((unsigned)s) << 16);
}
__device__ __forceinline__ bf16x8 pack8(float4 a, float4 b) {
  bf16x8 r;
  r[0]=(short)f2b(a.x); r[1]=(short)f2b(a.y); r[2]=(short)f2b(a.z); r[3]=(short)f2b(a.w);
  r[4]=(short)f2b(b.x); r[5]=(short)f2b(b.y); r[6]=(short)f2b(b.z); r[7]=(short)f2b(b.w);
  return r;
}

// ---- global->LDS 16B staging (wave-uniform LDS base + lane*16) ----
#if __has_builtin(__builtin_amdgcn_global_load_lds)
#define HAVE_GLL 1
__device__ __forceinline__ void gload16(const void* g, void* lds_base_uniform) {
  __builtin_amdgcn_global_load_lds(
      (const __attribute__((address_space(1))) void*)g,
      (__attribute__((address_space(3))) void*)lds_base_uniform, 16, 0, 0);
}
#else
#define HAVE_GLL 0
#endif

// ================= 64x64 bf16-MFMA GEMM (l2 proj only, K-split) =====
template<bool ABF, int BMODE, bool CBF, bool RELU, bool ROWBIAS>
__global__ __launch_bounds__(256) void mgemm(
    const void* __restrict__ Av, const void* __restrict__ Bv,
    const float* __restrict__ bias, void* __restrict__ Cv,
    int M, int N, int K, int lda, int ldb, long sB, long sC, int zShift)
{
  __shared__ unsigned short As[64][72];
  __shared__ unsigned short Bs[64][72];
  const int tid = threadIdx.x;
  const int n0 = blockIdx.x * 64, m0 = blockIdx.y * 64;
  const int zb = blockIdx.z;
  const int n_b = zb >> zShift;
  const int kBase = (zb & ((1 << zShift) - 1)) * K;
  const int lane = tid & 63;
  const int wave = tid >> 6;
  const int l15 = lane & 15, q = lane >> 4;
  const int m_off = (wave >> 1) * 32, n_off = (wave & 1) * 32;
  f32x4 acc[2][2] = {};

  for (int k0 = kBase; k0 < kBase + K; k0 += 64) {
    {
      int row = tid >> 2, kc = (tid & 3) * 8;
      int gm = m0 + row;
      bf16x8 v0 = (bf16x8)0, v1 = (bf16x8)0;
      if (gm < M) {
        if constexpr (ABF) {
          const unsigned short* A = (const unsigned short*)Av;
          v0 = *(const bf16x8*)&A[(size_t)gm*lda + k0 + kc];
          v1 = *(const bf16x8*)&A[(size_t)gm*lda + k0 + kc + 32];
        } else {
          const float* A = (const float*)Av;
          const float* p = &A[(size_t)gm*lda + k0 + kc];
          v0 = pack8(*(const float4*)p,      *(const float4*)(p+4));
          v1 = pack8(*(const float4*)(p+32), *(const float4*)(p+36));
        }
      }
      *(bf16x8*)&As[row][kc]    = v0;
      *(bf16x8*)&As[row][kc+32] = v1;
    }
    if constexpr (BMODE == 1) {
      const float* Bp = (const float*)Bv + (size_t)n_b * sB;
      int kr = tid >> 3, nc = (tid & 7) * 8;
      #pragma unroll
      for (int half = 0; half < 2; ++half) {
        int kk = kr + half*32;
        const float* p = &Bp[(size_t)(k0+kk)*ldb + n0 + nc];
        float v[8];
        if (n0 + nc + 7 < N) {
          float2 a0 = *(const float2*)p,     a1 = *(const float2*)(p+2);
          float2 a2 = *(const float2*)(p+4), a3 = *(const float2*)(p+6);
          v[0]=a0.x; v[1]=a0.y; v[2]=a1.x; v[3]=a1.y;
          v[4]=a2.x; v[5]=a2.y; v[6]=a3.x; v[7]=a3.y;
        } else {
          #pragma unroll
          for (int i=0;i<8;++i) v[i] = (n0+nc+i < N) ? p[i] : 0.f;
        }
        #pragma unroll
        for (int i=0;i<8;++i) Bs[nc+i][kk] = f2b(v[i]);
      }
    }
    __syncthreads();
    #pragma unroll
    for (int s = 0; s < 2; ++s) {
      bf16x8 a0 = *(const bf16x8*)&As[m_off      + l15][s*32 + q*8];
      bf16x8 a1 = *(const bf16x8*)&As[m_off + 16 + l15][s*32 + q*8];
      bf16x8 b0 = *(const bf16x8*)&Bs[n_off      + l15][s*32 + q*8];
      bf16x8 b1 = *(const bf16x8*)&Bs[n_off + 16 + l15][s*32 + q*8];
      acc[0][0] = __builtin_amdgcn_mfma_f32_16x16x32_bf16(a0, b0, acc[0][0], 0,0,0);
      acc[0][1] = __builtin_amdgcn_mfma_f32_16x16x32_bf16(a0, b1, acc[0][1], 0,0,0);
      acc[1][0] = __builtin_amdgcn_mfma_f32_16x16x32_bf16(a1, b0, acc[1][0], 0,0,0);
      acc[1][1] = __builtin_amdgcn_mfma_f32_16x16x32_bf16(a1, b1, acc[1][1], 0,0,0);
    }
    __syncthreads();
  }
  float* Cf = (float*)Cv + (size_t)zb * sC;
  unsigned short* Cb = (unsigned short*)Cv + (size_t)zb * sC;
  #pragma unroll
  for (int r = 0; r < 2; ++r) {
    #pragma unroll
    for (int c = 0; c < 2; ++c) {
      #pragma unroll
      for (int v = 0; v < 4; ++v) {
        int gm = m0 + m_off + r*16 + q*4 + v;
        int gn = n0 + n_off + c*16 + l15;
        if (gm < M && gn < N) {
          float o = acc[r][c][v];
          if (bias) o += ROWBIAS ? bias[gm] : bias[gn];
          if (RELU) o = fmaxf(o, 0.f);
          if constexpr (CBF) Cb[(size_t)gm*N + gn] = f2b(o);
          else               Cf[(size_t)gm*N + gn] = o;
        }
      }
    }
  }
}

// ---------- split-K reduce (l2) -> s2[o][n*HW+hw] layout ----------
__global__ __launch_bounds__(256) void proj_reduce2(
    const float* __restrict__ part, const float* __restrict__ bias,
    float* __restrict__ out, int HW, int S)
{
  int half = HW >> 1;
  int per_n = D_MODEL * half;
  int total = NBATCH * per_n;
  const float2* p2 = (const float2*)part;
  float2* o2 = (float2*)out;
  for (int i = blockIdx.x*256 + threadIdx.x; i < total; i += gridDim.x*256) {
    int n = i / per_n;
    int r = i - n*per_n;
    int o = r / half;
    int hw2 = r - o*half;
    float ax = 0.f, ay = 0.f;
    for (int s = 0; s < S; ++s) {
      float2 v = p2[((size_t)(n*S+s)*D_MODEL + o)*half + hw2];
      ax += v.x; ay += v.y;
    }
    float b = bias[o];
    o2[(size_t)o*HW + (size_t)n*half + hw2] = make_float2(ax+b, ay+b);
  }
}

// ======= 128x128 bf16xbf16 GEMM: single-buffer 32 KB LDS =======
template<bool CBF, bool RELU, bool RB>
__global__ __launch_bounds__(512) void gemm_bb(
    const unsigned short* __restrict__ A, const unsigned short* __restrict__ B,
    const float* __restrict__ bias, void* __restrict__ Cv,
    int M, int N, int K, int lda, int ldb)
{
  __shared__ unsigned short SA[8192];
  __shared__ unsigned short SB[8192];
  const int tid = threadIdx.x;
  const int lane = tid & 63, wave = tid >> 6;
  const int nwg = gridDim.x * gridDim.y;
  const int flat = blockIdx.y * gridDim.x + blockIdx.x;
  const int qn = nwg >> 3, rr = nwg & 7;
  const int xcd = flat & 7, lid = flat >> 3;
  const int swz = (xcd < rr ? xcd*(qn+1) : rr*(qn+1) + (xcd-rr)*qn) + lid;
  const int n0 = (swz % gridDim.x) * 128;
  const int m0 = (swz / gridDim.x) * 128;

  const int l15 = lane & 15, q = lane >> 4;
  const int m_off = (wave >> 2) * 64, n_off = (wave & 3) * 32;
  const int sr = lane >> 3;
  const int ssl = (lane & 7) ^ sr;
  const int rs = l15 & 7;
  f32x4 acc[4][2] = {};

  for (int k0 = 0; k0 < K; k0 += 64) {
    #pragma unroll
    for (int c = 0; c < 2; ++c) {
      int ch = wave*2 + c;
      const unsigned short* ga = A + (size_t)(m0 + ch*8 + sr)*lda + k0 + ssl*8;
      const unsigned short* gb = B + (size_t)(n0 + ch*8 + sr)*ldb + k0 + ssl*8;
#if HAVE_GLL
      gload16(ga, &SA[ch*512]);
      gload16(gb, &SB[ch*512]);
#else
      *(bf16x8*)&SA[ch*512 + lane*8] = *(const bf16x8*)ga;
      *(bf16x8*)&SB[ch*512 + lane*8] = *(const bf16x8*)gb;
#endif
    }
    __syncthreads();
    #pragma unroll
    for (int s = 0; s < 2; ++s) {
      int ps = ((s*4 + q) ^ rs) * 8;
      bf16x8 af[4], bfr[2];
      #pragma unroll
      for (int i = 0; i < 4; ++i)
        af[i] = *(const bf16x8*)&SA[(m_off + i*16 + l15)*64 + ps];
      #pragma unroll
      for (int j = 0; j < 2; ++j)
        bfr[j] = *(const bf16x8*)&SB[(n_off + j*16 + l15)*64 + ps];
      #pragma unroll
      for (int i = 0; i < 4; ++i)
        #pragma unroll
        for (int j = 0; j < 2; ++j)
          acc[i][j] = __builtin_amdgcn_mfma_f32_16x16x32_bf16(af[i], bfr[j], acc[i][j], 0,0,0);
    }
    __syncthreads();
  }

  float* Cf = (float*)Cv;
  unsigned short* Cb = (unsigned short*)Cv;
  #pragma unroll
  for (int i = 0; i < 4; ++i) {
    #pragma unroll
    for (int j = 0; j < 2; ++j) {
      #pragma unroll
      for (int v = 0; v < 4; ++v) {
        int gm = m0 + m_off + i*16 + q*4 + v;
        int gn = n0 + n_off + j*16 + l15;
        if (gm < M && gn < N) {
          float o = acc[i][j][v];
          if (bias) o += RB ? bias[gm] : bias[gn];
          if (RELU) o = fmaxf(o, 0.f);
          if constexpr (CBF) Cb[(size_t)gm*N + gn] = f2b(o);
          else               Cf[(size_t)gm*N + gn] = o;
        }
      }
    }
  }
}

// ======= merged value + off/attn GEMM (single-buffer, K=256) =======
// value C written as FP16 (for packed-fma deform); off/attn stays bf16.
__global__ __launch_bounds__(512) void gemm_vo(
    const unsigned short* __restrict__ Asrc, const unsigned short* __restrict__ Aq,
    const unsigned short* __restrict__ Bv,   const unsigned short* __restrict__ Bo,
    const float* __restrict__ bias_v, const float* __restrict__ bias_o,
    unsigned short* __restrict__ Cv, unsigned short* __restrict__ Co, int M)
{
  __shared__ unsigned short SA[8192];
  __shared__ unsigned short SB[8192];
  const int tid = threadIdx.x;
  const int lane = tid & 63, wave = tid >> 6;
  const int nwg = gridDim.x * gridDim.y;
  const int flat = blockIdx.y * gridDim.x + blockIdx.x;
  const int qn = nwg >> 3, rr = nwg & 7;
  const int xcd = flat & 7, lid = flat >> 3;
  const int swz = (xcd < rr ? xcd*(qn+1) : rr*(qn+1) + (xcd-rr)*qn) + lid;
  const int colid = swz % gridDim.x;
  const int m0 = (swz / gridDim.x) * 128;

  const unsigned short* A; const unsigned short* B;
  const float* bias; unsigned short* C; int N, n0; bool isv;
  if (colid < 2) { A = Asrc; B = Bv; bias = bias_v; C = Cv; N = 256; n0 = colid*128; isv = true; }
  else           { A = Aq;   B = Bo; bias = bias_o; C = Co; N = 288; n0 = (colid-2)*128; isv = false; }

  const int l15 = lane & 15, q = lane >> 4;
  const int m_off = (wave >> 2) * 64, n_off = (wave & 3) * 32;
  const int sr = lane >> 3;
  const int ssl = (lane & 7) ^ sr;
  const int rs = l15 & 7;
  f32x4 acc[4][2] = {};

  for (int k0 = 0; k0 < 256; k0 += 64) {
    #pragma unroll
    for (int c = 0; c < 2; ++c) {
      int ch = wave*2 + c;
      const unsigned short* ga = A + (size_t)(m0 + ch*8 + sr)*256 + k0 + ssl*8;
      const unsigned short* gb = B + (size_t)(n0 + ch*8 + sr)*256 + k0 + ssl*8;
#if HAVE_GLL
      gload16(ga, &SA[ch*512]);
      gload16(gb, &SB[ch*512]);
#else
      *(bf16x8*)&SA[ch*512 + lane*8] = *(const bf16x8*)ga;
      *(bf16x8*)&SB[ch*512 + lane*8] = *(const bf16x8*)gb;
#endif
    }
    __syncthreads();
    #pragma unroll
    for (int s = 0; s < 2; ++s) {
      int ps = ((s*4 + q) ^ rs) * 8;
      bf16x8 af[4], bfr[2];
      #pragma unroll
      for (int i = 0; i < 4; ++i)
        af[i] = *(const bf16x8*)&SA[(m_off + i*16 + l15)*64 + ps];
      #pragma unroll
      for (int j = 0; j < 2; ++j)
        bfr[j] = *(const bf16x8*)&SB[(n_off + j*16 + l15)*64 + ps];
      #pragma unroll
      for (int i = 0; i < 4; ++i)
        #pragma unroll
        for (int j = 0; j < 2; ++j)
          acc[i][j] = __builtin_amdgcn_mfma_f32_16x16x32_bf16(af[i], bfr[j], acc[i][j], 0,0,0);
    }
    __syncthreads();
  }

  #pragma unroll
  for (int i = 0; i < 4; ++i) {
    #pragma unroll
    for (int j = 0; j < 2; ++j) {
      #pragma unroll
      for (int v = 0; v < 4; ++v) {
        int gm = m0 + m_off + i*16 + q*4 + v;
        int gn = n0 + n_off + j*16 + l15;
        if (gm < M && gn < N) {
          float o = acc[i][j][v] + bias[gn];
          unsigned short bits;
          if (isv) { _Float16 hh = (_Float16)o; bits = *(unsigned short*)&hh; }
          else     { bits = f2b(o); }
          C[(size_t)gm*N + gn] = bits;
        }
      }
    }
  }
}

// ---------- feat [C,HW] fp32 -> featT [n*HW+hw][C] bf16 ----------
__global__ __launch_bounds__(256) void tconv(
    const float* __restrict__ feat, unsigned short* __restrict__ featT,
    int C, int HW)
{
  __shared__ float T[32][33];
  int hw0 = blockIdx.x*32, c0 = blockIdx.y*32, n = blockIdx.z;
  const float* base = feat + (size_t)n*C*HW;
  int tx = threadIdx.x & 31, ty = threadIdx.x >> 5;
  #pragma unroll
  for (int it=0; it<4; ++it) {
    int c = c0 + ty + it*8;
    int hw = hw0 + tx;
    T[ty+it*8][tx] = (hw < HW) ? base[(size_t)c*HW + hw] : 0.f;
  }
  __syncthreads();
  #pragma unroll
  for (int it=0; it<4; ++it) {
    int tl = ty + it*8;
    int tok = hw0 + tl;
    if (tok < HW) {
      featT[((size_t)n*HW + tok)*C + c0 + tx] = f2b(T[tx][tl]);
    }
  }
}

// ---------- one-time weight fp32->bf16 conversion (9 segments) ----------
struct W9 { const float* src[9]; unsigned short* dst[9]; int nv[9]; };
__global__ __launch_bounds__(256) void wconv(W9 w)
{
  int s = blockIdx.y;
  const float4* src = (const float4*)w.src[s];
  unsigned short* dst = w.dst[s];
  int n = w.nv[s];
  for (int i = blockIdx.x*256 + threadIdx.x; i < n; i += gridDim.x*256) {
    float4 v = src[i];
    u16x4 o = { f2b(v.x), f2b(v.y), f2b(v.z), f2b(v.w) };
    *(u16x4*)(dst + (size_t)i*4) = o;
  }
}

// ---------- concat off/attn biases ----------
__global__ __launch_bounds__(288) void biascat(
    const float* __restrict__ b_off, const float* __restrict__ b_attn,
    float* __restrict__ out)
{
  int i = threadIdx.x;
  out[i] = (i < 192) ? b_off[i] : b_attn[i - 192];
}

// ---------- GN stage 1 over s2[o][n*HW+hw] layout ----------
__global__ __launch_bounds__(256) void gn_partial2(
    const float* __restrict__ s2, float* __restrict__ partials, int HW)
{
  int g = blockIdx.x, n = blockIdx.y, c = blockIdx.z;
  int NHW = HW*2;
  int nvec2 = HW >> 1;
  int total = nvec2*8;
  float sum = 0.f, sq = 0.f;
  for (int j = c*256 + threadIdx.x; j < total; j += 2048) {
    int r = j / nvec2;
    int v = j - r*nvec2;
    const float2 x = *(const float2*)(s2 + (size_t)(g*8+r)*NHW + (size_t)n*HW + v*2);
    sum += x.x + x.y;
    sq  += x.x*x.x + x.y*x.y;
  }
  #pragma unroll
  for (int m=32;m;m>>=1){ sum += __shfl_xor(sum,m,64); sq += __shfl_xor(sq,m,64); }
  __shared__ float s1[4], s2s[4];
  int w = threadIdx.x >> 6;
  if ((threadIdx.x & 63) == 0) { s1[w]=sum; s2s[w]=sq; }
  __syncthreads();
  if (threadIdx.x == 0) {
    partials[(((size_t)n*32+g)*8 + c)*2]     = s1[0]+s1[1]+s1[2]+s1[3];
    partials[(((size_t)n*32+g)*8 + c)*2 + 1] = s2s[0]+s2s[1]+s2s[2]+s2s[3];
  }
}

// ---------- GN apply + transpose + FUSED q/src_bf emission ----------
// s2[o][n*HW+hw] -> src fp32 token-major, src_bf bf16, q bf16 (src+pos+lvl_emb)
// NOTE (r17 bug fix): featT must NOT alias q_b — featT now lives in value_b.
__global__ __launch_bounds__(256) void gn_apply2(
    const float* __restrict__ s2, const float* __restrict__ partials,
    const float* __restrict__ gw, const float* __restrict__ gb,
    const float* __restrict__ le,             // level_embed + lvl*256
    float* __restrict__ src, unsigned short* __restrict__ srcbf,
    unsigned short* __restrict__ qb,
    int HW, int loff, int W, float invW, float invH2pi, float invW2pi)
{
  __shared__ float T[32][33];
  __shared__ float smu[4], srs[4];
  int tx = threadIdx.x & 31, ty = threadIdx.x >> 5;
  int hw0 = blockIdx.x*32, o0 = blockIdx.y*32, n = blockIdx.z;
  int NHW = HW*2;
  if (threadIdx.x < 4) {
    int g = (o0 >> 3) + threadIdx.x;
    float S = 0.f, Q = 0.f;
    #pragma unroll
    for (int c = 0; c < 8; ++c) {
      S += partials[(((size_t)n*32+g)*8 + c)*2];
      Q += partials[(((size_t)n*32+g)*8 + c)*2 + 1];
    }
    float inv = 1.f/(float)(8*HW);
    float mu = S*inv;
    float var = Q*inv - mu*mu;
    smu[threadIdx.x] = mu;
    srs[threadIdx.x] = rsqrtf(var + 1e-5f);
  }
  __syncthreads();
  #pragma unroll
  for (int it=0; it<4; ++it) {
    int ol = ty + it*8;
    int o = o0 + ol;
    int hw = hw0 + tx;
    float v = 0.f;
    if (hw < HW) {
      v = (s2[(size_t)o*NHW + (size_t)n*HW + hw] - smu[ol>>3])*srs[ol>>3]*gw[o] + gb[o];
    }
    T[ol][tx] = v;
  }
  __syncthreads();
  int d = o0 + tx;
  int m = (d & 127) >> 1;
  float invt = __expf((float)m * -0.14391156516f);   // 10000^(-m/64)
  float lev  = le[d];
  #pragma unroll
  for (int it=0; it<4; ++it) {
    int tl = ty + it*8;
    int tok = hw0 + tl;
    if (tok < HW) {
      size_t idx = ((size_t)n*LQ + loff + tok)*D_MODEL + d;
      float v = T[tx][tl];
      src[idx] = v;
      srcbf[idx] = f2b(v);
      int i = __float2int_rd(((float)tok + 0.5f) * invW);
      int j = tok - i*W;
      float ang = ((d < 128) ? (float)(i+1)*invH2pi : (float)(j+1)*invW2pi) * invt;
      float pe = (d & 1) ? __cosf(ang) : __sinf(ang);
      qb[idx] = f2b(v + pe + lev);
    }
  }
}

// ---------- deformable sampling v3: fp16 value + packed v_pk_fma_f16 ----------
__global__ __launch_bounds__(256) void deform_sample(
    const unsigned short* __restrict__ value, const unsigned short* __restrict__ offaw,
    unsigned short* __restrict__ accb)
{
  int idx = blockIdx.x*256 + threadIdx.x;
  if (idx >= NT*8*4) return;
  int quarter = idx & 3;
  int h = (idx >> 2) & 7;
  int row = idx >> 5;
  int n = (row >= LQ) ? 1 : 0;
  int tok = row - n*LQ;

  float bxs0, bxs1, bxs2, bys0, bys1, bys2;
  if (tok < 15200) {
    int ti = tok/152, tj = tok - ti*152;
    float bx = tj + 0.5f, by = ti + 0.5f;
    bxs0 = bx - 0.5f;         bys0 = by - 0.5f;
    bxs1 = bx*0.5f - 0.5f;    bys1 = by*0.5f - 0.5f;
    bxs2 = bx*0.25f - 0.5f;   bys2 = by*0.25f - 0.5f;
  } else if (tok < 19000) {
    int hw = tok - 15200; int ti = hw/76, tj = hw - ti*76;
    float bx = tj + 0.5f, by = ti + 0.5f;
    bxs0 = bx*2.f - 0.5f;     bys0 = by*2.f - 0.5f;
    bxs1 = bx - 0.5f;         bys1 = by - 0.5f;
    bxs2 = bx*0.5f - 0.5f;    bys2 = by*0.5f - 0.5f;
  } else {
    int hw = tok - 19000; int ti = hw/38, tj = hw - ti*38;
    float bx = tj + 0.5f, by = ti + 0.5f;
    bxs0 = bx*4.f - 0.5f;     bys0 = by*4.f - 0.5f;
    bxs1 = bx*2.f - 0.5f;     bys1 = by*2.f - 0.5f;
    bxs2 = bx - 0.5f;         bys2 = by - 0.5f;
  }
  const float bxs[3] = {bxs0, bxs1, bxs2};
  const float bys[3] = {bys0, bys1, bys2};

  const unsigned short* offr = offaw + (size_t)row*288 + h*24;
  const unsigned short* awr  = offaw + (size_t)row*288 + 192 + h*12;
  float off[24];
  {
    u16x8 o0 = *(const u16x8*)offr;
    u16x8 o1 = *(const u16x8*)(offr+8);
    u16x8 o2 = *(const u16x8*)(offr+16);
    #pragma unroll
    for (int c=0;c<8;++c){ off[c]=b2f(o0[c]); off[8+c]=b2f(o1[c]); off[16+c]=b2f(o2[c]); }
  }
  float lg[12];
  {
    u16x4 a0 = *(const u16x4*)awr;
    u16x4 a1 = *(const u16x4*)(awr+4);
    u16x4 a2 = *(const u16x4*)(awr+8);
    #pragma unroll
    for (int c=0;c<4;++c){ lg[c]=b2f(a0[c]); lg[4+c]=b2f(a1[c]); lg[8+c]=b2f(a2[c]); }
  }
  float mx = -1e30f;
  #pragma unroll
  for (int i=0;i<12;++i) mx = fmaxf(mx, lg[i]);
  float ssum = 0.f;
  #pragma unroll
  for (int i=0;i<12;++i){ lg[i] = __expf(lg[i]-mx); ssum += lg[i]; }
  float sinv = 1.f/ssum;

  h16x2 acc2[4] = {};
  const int HH[3]={100,50,25}, WW[3]={152,76,38}, OO[3]={0,15200,19000};
  int chbase = h*32 + quarter*8;
  const _Float16* vhalf = (const _Float16*)value;
  #pragma unroll
  for (int lvl=0; lvl<3; ++lvl) {
    const int H=HH[lvl], W=WW[lvl], lo=OO[lvl];
    const _Float16* vbase = vhalf + ((size_t)(n*LQ + lo)*D_MODEL) + chbase;
    #pragma unroll
    for (int p=0; p<4; ++p) {
      float ox = off[lvl*8 + p*2];
      float oy = off[lvl*8 + p*2 + 1];
      float a  = lg[lvl*4 + p] * sinv;
      float x = bxs[lvl] + ox;
      float y = bys[lvl] + oy;
      float x0f = floorf(x), y0f = floorf(y);
      float wx = x - x0f, wy = y - y0f;
      int x0 = (int)x0f, y0 = (int)y0f;
      float w00 = (1.f-wx)*(1.f-wy)*a, w10 = wx*(1.f-wy)*a;
      float w01 = (1.f-wx)*wy*a,       w11 = wx*wy*a;
      if ((unsigned)x0 < (unsigned)(W-1) && (unsigned)y0 < (unsigned)(H-1)) {
        const h16x2* p00 = (const h16x2*)(vbase + (size_t)(y0*W + x0)*D_MODEL);
        const h16x2* p10 = (const h16x2*)(vbase + (size_t)(y0*W + x0 + 1)*D_MODEL);
        const h16x2* p01 = (const h16x2*)(vbase + (size_t)((y0+1)*W + x0)*D_MODEL);
        const h16x2* p11 = (const h16x2*)(vbase + (size_t)((y0+1)*W + x0 + 1)*D_MODEL);
        _Float16 h00 = (_Float16)w00, h10 = (_Float16)w10;
        _Float16 h01 = (_Float16)w01, h11 = (_Float16)w11;
        h16x2 wp00 = {h00,h00}, wp10 = {h10,h10}, wp01 = {h01,h01}, wp11 = {h11,h11};
        #pragma unroll
        for (int k=0;k<4;++k) {
          acc2[k] += wp00*p00[k];
          acc2[k] += wp10*p10[k];
          acc2[k] += wp01*p01[k];
          acc2[k] += wp11*p11[k];
        }
      } else {
        float tw[4] = { w00, w10, w01, w11 };
        #pragma unroll
        for (int t=0; t<4; ++t) {
          int xi = x0 + (t & 1), yi = y0 + (t >> 1);
          if (xi >= 0 && xi < W && yi >= 0 && yi < H) {
            _Float16 wh = (_Float16)tw[t];
            h16x2 wp = {wh, wh};
            const h16x2* vr = (const h16x2*)(vbase + (size_t)(yi*W + xi)*D_MODEL);
            #pragma unroll
            for (int k=0;k<4;++k) acc2[k] += wp*vr[k];
          }
        }
      }
    }
  }
  unsigned short* o = accb + (size_t)row*D_MODEL + chbase;
  u16x8 ov;
  #pragma unroll
  for (int k=0;k<4;++k) {
    ov[k*2]   = f2b((float)acc2[k][0]);
    ov[k*2+1] = f2b((float)acc2[k][1]);
  }
  *(u16x8*)o = ov;
}

// ---------- out = LN(A+B)*g+b (+ optional bf16 mirror) ----------
template<bool EMITBF>
__global__ __launch_bounds__(256) void ln_add(
    const float* __restrict__ A, const float* __restrict__ B,
    const float* __restrict__ g, const float* __restrict__ b,
    float* __restrict__ out, unsigned short* __restrict__ outbf, int rows)
{
  int wid = (blockIdx.x * 256 + threadIdx.x) >> 6;
  int lane = threadIdx.x & 63;
  if (wid >= rows) return;
  size_t base = (size_t)wid * D_MODEL;
  float4 va = *(const float4*)&A[base + lane*4];
  float4 vb = *(const float4*)&B[base + lane*4];
  float v[4] = {va.x+vb.x, va.y+vb.y, va.z+vb.z, va.w+vb.w};
  float s = v[0]+v[1]+v[2]+v[3];
  #pragma unroll
  for (int m=32; m; m>>=1) s += __shfl_xor(s, m, 64);
  float mu = s * (1.f/256.f);
  float qq = 0.f;
  #pragma unroll
  for (int i=0;i<4;++i){ float d=v[i]-mu; qq += d*d; }
  #pragma unroll
  for (int m=32; m; m>>=1) qq += __shfl_xor(qq, m, 64);
  float rstd = rsqrtf(qq*(1.f/256.f) + 1e-5f);
  float o[4];
  #pragma unroll
  for (int i=0;i<4;++i){
    int d = lane*4+i;
    o[i] = (v[i]-mu)*rstd*g[d] + b[d];
  }
  *(float4*)&out[base + lane*4] = make_float4(o[0],o[1],o[2],o[3]);
  if constexpr (EMITBF) {
    u16x4 ob = { f2b(o[0]), f2b(o[1]), f2b(o[2]), f2b(o[3]) };
    *(u16x4*)&outbf[base + lane*4] = ob;
  }
}

// ---------- point head bilinear (bf16 out) ----------
__global__ __launch_bounds__(256) void point_sample(
    const float* __restrict__ x2, const float* __restrict__ pc,
    unsigned short* __restrict__ pf)
{
  int pidx = blockIdx.x;
  int n = pidx / 1000;
  float px = pc[(size_t)pidx*2], py = pc[(size_t)pidx*2+1];
  float x = ((2.f*px)*152.f - 1.f)*0.5f;
  float y = ((2.f*py)*100.f - 1.f)*0.5f;
  float x0f=floorf(x), y0f=floorf(y);
  float wx=x-x0f, wy=y-y0f;
  int x0=(int)x0f, y0=(int)y0f;
  int d = threadIdx.x;
  float accv = 0.f;
  #pragma unroll
  for (int t=0;t<4;++t) {
    int xi = x0 + (t&1), yi = y0 + (t>>1);
    float w = ((t&1)?wx:(1.f-wx)) * ((t>>1)?wy:(1.f-wy));
    if (xi>=0 && xi<152 && yi>=0 && yi<100) {
      accv += w * x2[((size_t)(n*LQ + yi*152 + xi))*D_MODEL + d];
    }
  }
  pf[(size_t)pidx*D_MODEL + d] = f2b(accv);
}

__global__ void copy_gt(const int* __restrict__ gt, float* __restrict__ out, int nels)
{
  int i = blockIdx.x*256 + threadIdx.x;
  if (i < nels) out[i] = (float)gt[i];
}

extern "C" void kernel_launch(void* const* d_in, const int* in_sizes, int n_in,
                              void* d_out, int out_size, void* d_ws, size_t ws_size,
                              hipStream_t stream)
{
  const float* feat[3]  = {(const float*)d_in[0], (const float*)d_in[1], (const float*)d_in[2]};
  const float* pc       = (const float*)d_in[3];
  const int*   gt       = (const int*)d_in[4];
  const float* projw[3] = {(const float*)d_in[5],  (const float*)d_in[9],  (const float*)d_in[13]};
  const float* projb[3] = {(const float*)d_in[6],  (const float*)d_in[10], (const float*)d_in[14]};
  const float* gng[3]   = {(const float*)d_in[7],  (const float*)d_in[11], (const float*)d_in[15]};
  const float* gnb[3]   = {(const float*)d_in[8],  (const float*)d_in[12], (const float*)d_in[16]};
  const float* level_embed = (const float*)d_in[17];
  const float* w_off  = (const float*)d_in[18];
  const float* b_off  = (const float*)d_in[19];
  const float* w_attn = (const float*)d_in[20];
  const float* b_attn = (const float*)d_in[21];
  const float* w_val  = (const float*)d_in[22];
  const float* b_val  = (const float*)d_in[23];
  const float* w_out  = (const float*)d_in[24];
  const float* b_out  = (const float*)d_in[25];
  const float* ln1g   = (const float*)d_in[26];
  const float* ln1b   = (const float*)d_in[27];
  const float* ln2g   = (const float*)d_in[28];
  const float* ln2b   = (const float*)d_in[29];
  const float* wff1   = (const float*)d_in[30];
  const float* bff1   = (const float*)d_in[31];
  const float* wff2   = (const float*)d_in[32];
  const float* bff2   = (const float*)d_in[33];
  const float* fcw    = (const float*)d_in[34];
  const float* fcb    = (const float*)d_in[35];

  // ---- workspace layout ----
  float* ws    = (float*)d_ws;
  float* s_tmp = ws;                                             // 10,214,400 f
  unsigned short* q_b     = (unsigned short*)(s_tmp + 10214400); // 10,214,400 us
  unsigned short* value_b = q_b + 10214400;                      // 10,214,400 us
  float* srcb  = (float*)(value_b + 10214400);                   // 10,214,400 f
  float* xreg  = srcb + 10214400;                                // 10,214,400 f
  unsigned short* offaw   = (unsigned short*)(xreg + 10214400);  // 11,491,200 us
  unsigned short* wbf     = offaw + 11491200;                    //  4,333,568 us
  float* partials = (float*)(wbf + 4333568);                     // 1024 f
  float* boffaw   = partials + 1024;                             // 288 f

  unsigned short* wv_bf  = wbf;
  unsigned short* wof_bf = wbf + 65536;
  unsigned short* wat_bf = wbf + 114688;
  unsigned short* wou_bf = wbf + 139264;
  unsigned short* wf1_bf = wbf + 204800;
  unsigned short* wf2_bf = wbf + 466944;
  unsigned short* wfc_bf = wbf + 729088;
  unsigned short* wp0_bf = wbf + 3940352;   // 131,072 us (256x512)
  unsigned short* wp1_bf = wbf + 4071424;   // 262,144 us (256x1024)

  // featT lives in value_b (l0 spills into srcb's head — both dead then).
  // q_b is NEVER aliased by featT (r17 bug fix).
  unsigned short* featT = value_b;
  float* kpart = (float*)offaw;                      // l2 split-K partials
  unsigned short* src_bf = (unsigned short*)xreg;    // bf16 src mirror (gn_apply2)
  unsigned short* acc_b = q_b;                       // q dead after step 3
  unsigned short* xb_bf = offaw;                     // off/aw dead after step 4
  unsigned short* hbuf  = (unsigned short*)s_tmp;    // FULL h spans s_tmp+q_b+value_b
  unsigned short* pf    = value_b;                   // h dead after FFN2
  float* ybuf = srcb;                                // src dead after LN1
  float* x2   = s_tmp;                               // h dead after FFN2

  // 0) weight conversion + bias concat
  W9 w9;
  w9.src[0]=w_val;    w9.dst[0]=wv_bf;  w9.nv[0]=65536/4;
  w9.src[1]=w_off;    w9.dst[1]=wof_bf; w9.nv[1]=49152/4;
  w9.src[2]=w_attn;   w9.dst[2]=wat_bf; w9.nv[2]=24576/4;
  w9.src[3]=w_out;    w9.dst[3]=wou_bf; w9.nv[3]=65536/4;
  w9.src[4]=wff1;     w9.dst[4]=wf1_bf; w9.nv[4]=262144/4;
  w9.src[5]=wff2;     w9.dst[5]=wf2_bf; w9.nv[5]=262144/4;
  w9.src[6]=fcw;      w9.dst[6]=wfc_bf; w9.nv[6]=3211264/4;
  w9.src[7]=projw[0]; w9.dst[7]=wp0_bf; w9.nv[7]=131072/4;
  w9.src[8]=projw[1]; w9.dst[8]=wp1_bf; w9.nv[8]=262144/4;
  wconv<<<dim3(512, 9), 256, 0, stream>>>(w9);
  biascat<<<1, 288, 0, stream>>>(b_off, b_attn, boffaw);

  const float PI2 = 6.28318530717958647692f;
  // 1) proj levels (gn_apply2 fused with q/src_bf emission)
  {  // level 0: HW=15200, K=512
    tconv<<<dim3(475, 16, 2), 256, 0, stream>>>(feat[0], featT, 512, 15200);
    gemm_bb<false,false,true><<<dim3(238, 2), 512, 0, stream>>>(
        wp0_bf, featT, projb[0], s_tmp, 256, 30400, 512, 512, 512);
    gn_partial2<<<dim3(32, 2, 8), 256, 0, stream>>>(s_tmp, partials, 15200);
    gn_apply2<<<dim3(475, 8, 2), 256, 0, stream>>>(
        s_tmp, partials, gng[0], gnb[0], level_embed, srcb, src_bf, q_b,
        15200, 0, 152, 1.0f/152.f, PI2/(100.f+1e-6f), PI2/(152.f+1e-6f));
  }
  {  // level 1: HW=3800, K=1024 (featT fits in value_b alone)
    tconv<<<dim3(119, 32, 2), 256, 0, stream>>>(feat[1], featT, 1024, 3800);
    gemm_bb<false,false,true><<<dim3(60, 2), 512, 0, stream>>>(
        wp1_bf, featT, projb[1], s_tmp, 256, 7600, 1024, 1024, 1024);
    gn_partial2<<<dim3(32, 2, 8), 256, 0, stream>>>(s_tmp, partials, 3800);
    gn_apply2<<<dim3(119, 8, 2), 256, 0, stream>>>(
        s_tmp, partials, gng[1], gnb[1], level_embed + 256, srcb, src_bf, q_b,
        3800, 15200, 76, 1.0f/76.f, PI2/(50.f+1e-6f), PI2/(76.f+1e-6f));
  }
  {  // level 2: HW=950, K=2048, split-K S=4 (kpart in offaw)
    mgemm<false,1,false,false,true><<<dim3(15, 4, 8), 256, 0, stream>>>(
        projw[2], feat[2], nullptr, kpart, D_MODEL, 950, 512, 2048, 950,
        (long)2048*950, (long)D_MODEL*950, 2);
    int total2 = NBATCH * D_MODEL * (950 >> 1);
    int gr = (total2 + 255) / 256; if (gr > 2048) gr = 2048;
    proj_reduce2<<<gr, 256, 0, stream>>>(kpart, projb[2], s_tmp, 950, 4);
    gn_partial2<<<dim3(32, 2, 8), 256, 0, stream>>>(s_tmp, partials, 950);
    gn_apply2<<<dim3(30, 8, 2), 256, 0, stream>>>(
        s_tmp, partials, gng[2], gnb[2], level_embed + 512, srcb, src_bf, q_b,
        950, 19000, 38, 1.0f/38.f, PI2/(25.f+1e-6f), PI2/(38.f+1e-6f));
  }

  // 3) value (fp16 C, overwrites featT) + off/attn (bf16 C) in ONE dispatch
  int gm128 = (NT + 127) / 128;
  gemm_vo<<<dim3(5, gm128), 512, 0, stream>>>(
      src_bf, q_b, wv_bf, wof_bf, b_val, boffaw, value_b, offaw, NT);

  // 4) deformable sampling (fp16 packed fma) -> acc bf16 (q region)
  deform_sample<<<(NT*8*4 + 255)/256, 256, 0, stream>>>(value_b, offaw, acc_b);

  // 5) out-proj ; x = LN(src + attn) -> xreg + xb_bf
  gemm_bb<false,false,false><<<dim3(2, gm128), 512, 0, stream>>>(
      acc_b, wou_bf, b_out, s_tmp, NT, 256, 256, 256, 256);
  ln_add<true><<<(NT+3)/4, 256, 0, stream>>>(srcb, s_tmp, ln1g, ln1b, xreg, xb_bf, NT);

  // 6) FFN, un-chunked: h spans s_tmp+q_b+value_b; y -> srcb
  gemm_bb<true,true,false><<<dim3(8, gm128), 512, 0, stream>>>(
      xb_bf, wf1_bf, bff1, hbuf, NT, 1024, 256, 256, 256);
  gemm_bb<false,false,false><<<dim3(2, gm128), 512, 0, stream>>>(
      hbuf, wf2_bf, bff2, ybuf, NT, 256, 1024, 1024, 1024);

  // 7) x2 = LN(x + y) -> s_tmp
  ln_add<false><<<(NT+3)/4, 256, 0, stream>>>(xreg, ybuf, ln2g, ln2b, x2, nullptr, NT);

  // 8) point bilinear -> pf bf16, fc GEMM -> d_out, gt tail
  point_sample<<<2000, 256, 0, stream>>>(x2, pc, pf);
  gemm_bb<false,true,false><<<dim3(98, (2000+127)/128), 512, 0, stream>>>(
      pf, wfc_bf, fcb, (float*)d_out, 2000, 12544, 256, 256, 256);
  copy_gt<<<8, 256, 0, stream>>>(gt, (float*)d_out + (size_t)2000*12544, 2000);
}